// Round 2
// baseline (370.121 us; speedup 1.0000x reference)
//
#include <hip/hip_runtime.h>
#include <stdint.h>

// AffineCoupling: B=65536 rows, DIM=128, D_IN=64, HID=512, 2 extra hidden layers.
// Fused bf16-MFMA. 64 rows/block, 8 waves, each wave owns 64 neurons x 64 rows
// (4x4 16x16x32 frags). LDS = h activations only (64KB) -> 2 blocks/CU.
// log_s stashed in out's z2 region between s- and t-MLP (same-thread RAW).

#define NROWS 65536

// bf16 weight scratch layout (element offsets in d_ws)
#define OFF_S_WIN   0
#define OFF_S_WHID  32768
#define OFF_S_WOUT  557056
#define OFF_T_WIN   589824
#define OFF_T_WHID  622592
#define OFF_T_WOUT  1146880
#define W_ELEMS     1179648

typedef __attribute__((ext_vector_type(8))) short short8;
typedef __attribute__((ext_vector_type(4))) float f32x4;

__device__ __forceinline__ uint32_t f2bf1(float f) {
  uint32_t u = __float_as_uint(f);
  return (u + 0x7fffu + ((u >> 16) & 1u)) >> 16;   // RNE
}
__device__ __forceinline__ uint32_t pk2bf(float a, float b) {
  return f2bf1(a) | (f2bf1(b) << 16);
}

// ---------------- weight fp32 -> bf16 prologue ----------------
__global__ void cvt_weights(const float* __restrict__ sWin, const float* __restrict__ sWhid,
                            const float* __restrict__ sWout, const float* __restrict__ tWin,
                            const float* __restrict__ tWhid, const float* __restrict__ tWout,
                            uint16_t* __restrict__ wbf) {
  int g = blockIdx.x * blockDim.x + threadIdx.x;
  int e = g * 4;
  if (e >= W_ELEMS) return;
  const float* src; int off;
  if      (e < OFF_S_WHID) { src = sWin;  off = e; }
  else if (e < OFF_S_WOUT) { src = sWhid; off = e - OFF_S_WHID; }
  else if (e < OFF_T_WIN)  { src = sWout; off = e - OFF_S_WOUT; }
  else if (e < OFF_T_WHID) { src = tWin;  off = e - OFF_T_WIN; }
  else if (e < OFF_T_WOUT) { src = tWhid; off = e - OFF_T_WHID; }
  else                     { src = tWout; off = e - OFF_T_WOUT; }
  f32x4 v = *(const f32x4*)(src + off);
  uint2 r; r.x = pk2bf(v.x, v.y); r.y = pk2bf(v.z, v.w);
  *(uint2*)(wbf + e) = r;
}

// ---------------- fragment loaders ----------------
// A-frag (weights, row-major [M][K]): lane l supplies W[m=base+(l&15)][k=(l>>4)*8+j]
template<bool BF>
__device__ __forceinline__ short8 ldW(const uint16_t* __restrict__ wb,
                                      const float* __restrict__ wf, int idx) {
  if (BF) {
    return *(const short8*)(wb + idx);
  } else {  // fallback: convert fp32 weights on the fly
    f32x4 x = *(const f32x4*)(wf + idx);
    f32x4 y = *(const f32x4*)(wf + idx + 4);
    short8 r;
    r[0] = (short)f2bf1(x.x); r[1] = (short)f2bf1(x.y);
    r[2] = (short)f2bf1(x.z); r[3] = (short)f2bf1(x.w);
    r[4] = (short)f2bf1(y.x); r[5] = (short)f2bf1(y.y);
    r[6] = (short)f2bf1(y.z); r[7] = (short)f2bf1(y.w);
    return r;
  }
}

// B-frag (activations h^T from LDS, row stride 1024B):
// XOR swizzle (row&7)<<4 breaks same-bank column access (2-way = free).
__device__ __forceinline__ short8 ldsB(const uint16_t* buf, int row, int k) {
  int byte = (row * 1024 + k * 2) ^ ((row & 7) << 4);
  return *(const short8*)((const char*)buf + byte);
}

// ---------------- epilogue: bias + relu + pack + swizzled LDS store ----------------
__device__ __forceinline__ void store_h(f32x4 acc[4][4], const float* __restrict__ bias,
                                        uint16_t* hdst, int wave, int lane) {
  const int l15 = lane & 15, lq = lane >> 4;
  __syncthreads();   // all waves done READING h (h is read+written in place)
  #pragma unroll
  for (int rt = 0; rt < 4; ++rt) {
    const int n0 = wave * 64 + rt * 16 + lq * 4;
    f32x4 bv = *(const f32x4*)(bias + n0);
    #pragma unroll
    for (int ct = 0; ct < 4; ++ct) {
      const int row = ct * 16 + l15;
      f32x4 v = acc[rt][ct] + bv;
      uint2 p;
      p.x = pk2bf(fmaxf(v.x, 0.f), fmaxf(v.y, 0.f));
      p.y = pk2bf(fmaxf(v.z, 0.f), fmaxf(v.w, 0.f));
      int byte = (row * 1024 + n0 * 2) ^ ((row & 7) << 4);
      *(uint2*)((char*)hdst + byte) = p;
    }
  }
  __syncthreads();
}

// ---------------- layer 1: h = relu(W @ z1^T + b), K=64, B built from global z ----------------
template<bool BF>
__device__ __forceinline__ void dense_in(
    const uint16_t* __restrict__ wb, const float* __restrict__ wf,
    const float* __restrict__ bias, const float* __restrict__ z, long rowbase,
    uint16_t* hdst, int wave, int lane) {
  const int l15 = lane & 15, lq = lane >> 4;
  f32x4 acc[4][4];
  #pragma unroll
  for (int rt = 0; rt < 4; ++rt)
    #pragma unroll
    for (int ct = 0; ct < 4; ++ct) acc[rt][ct] = (f32x4){0.f, 0.f, 0.f, 0.f};
  const int wbase = (wave * 64 + l15) * 64 + lq * 8;
  #pragma unroll
  for (int k0 = 0; k0 < 64; k0 += 32) {
    short8 a[4];
    #pragma unroll
    for (int rt = 0; rt < 4; ++rt) a[rt] = ldW<BF>(wb, wf, wbase + rt * 1024 + k0);
    #pragma unroll
    for (int ct = 0; ct < 4; ++ct) {
      const float* zp = z + (rowbase + ct * 16 + l15) * 128 + lq * 8 + k0;
      f32x4 u = *(const f32x4*)zp;
      f32x4 v = *(const f32x4*)(zp + 4);
      short8 b;
      b[0] = (short)f2bf1(u.x); b[1] = (short)f2bf1(u.y);
      b[2] = (short)f2bf1(u.z); b[3] = (short)f2bf1(u.w);
      b[4] = (short)f2bf1(v.x); b[5] = (short)f2bf1(v.y);
      b[6] = (short)f2bf1(v.z); b[7] = (short)f2bf1(v.w);
      #pragma unroll
      for (int rt = 0; rt < 4; ++rt)
        acc[rt][ct] = __builtin_amdgcn_mfma_f32_16x16x32_bf16(a[rt], b, acc[rt][ct], 0, 0, 0);
    }
  }
  store_h(acc, bias, hdst, wave, lane);
}

// ---------------- hidden layer: h = relu(W @ h^T + b), K=512, A-frag prefetch ----------------
template<bool BF>
__device__ __forceinline__ void dense_relu512(
    const uint16_t* __restrict__ wb, const float* __restrict__ wf,
    const float* __restrict__ bias, uint16_t* hbuf, int wave, int lane) {
  const int l15 = lane & 15, lq = lane >> 4;
  f32x4 acc[4][4];
  #pragma unroll
  for (int rt = 0; rt < 4; ++rt)
    #pragma unroll
    for (int ct = 0; ct < 4; ++ct) acc[rt][ct] = (f32x4){0.f, 0.f, 0.f, 0.f};
  const int wbase = (wave * 64 + l15) * 512 + lq * 8;

  short8 an[4];
  #pragma unroll
  for (int rt = 0; rt < 4; ++rt) an[rt] = ldW<BF>(wb, wf, wbase + rt * 8192);

  #pragma unroll 2
  for (int k0 = 0; k0 < 512; k0 += 32) {
    short8 ac[4];
    #pragma unroll
    for (int rt = 0; rt < 4; ++rt) ac[rt] = an[rt];
    if (k0 + 32 < 512) {
      #pragma unroll
      for (int rt = 0; rt < 4; ++rt)
        an[rt] = ldW<BF>(wb, wf, wbase + rt * 8192 + k0 + 32);
    }
    #pragma unroll
    for (int ct = 0; ct < 4; ++ct) {
      short8 b = ldsB(hbuf, ct * 16 + l15, lq * 8 + k0);
      #pragma unroll
      for (int rt = 0; rt < 4; ++rt)
        acc[rt][ct] = __builtin_amdgcn_mfma_f32_16x16x32_bf16(ac[rt], b, acc[rt][ct], 0, 0, 0);
    }
  }
  store_h(acc, bias, hbuf, wave, lane);
}

// ---------------- output layer: 64 neurons, waves 0..3 (wave = row-tile) ----------------
template<bool BF>
__device__ __forceinline__ void final_layer(
    const uint16_t* __restrict__ wb, const float* __restrict__ wf,
    const uint16_t* hbuf, int wave, int lane, f32x4 acc[4]) {
  const int l15 = lane & 15, lq = lane >> 4;
  #pragma unroll
  for (int rt = 0; rt < 4; ++rt) acc[rt] = (f32x4){0.f, 0.f, 0.f, 0.f};
  const int wbase = l15 * 512 + lq * 8;
  #pragma unroll 4
  for (int k0 = 0; k0 < 512; k0 += 32) {
    short8 b = ldsB(hbuf, wave * 16 + l15, lq * 8 + k0);
    #pragma unroll
    for (int rt = 0; rt < 4; ++rt) {
      short8 a = ldW<BF>(wb, wf, wbase + rt * 16 * 512 + k0);
      acc[rt] = __builtin_amdgcn_mfma_f32_16x16x32_bf16(a, b, acc[rt], 0, 0, 0);
    }
  }
}

// ---------------- fused coupling kernel: 64 rows/block, 8 waves ----------------
template<bool BF>
__global__ __launch_bounds__(512, 4) void coupling(
    const float* __restrict__ z,
    const float* __restrict__ sWin, const float* __restrict__ sbin,
    const float* __restrict__ sWhid, const float* __restrict__ sbhid,
    const float* __restrict__ sWout, const float* __restrict__ sbout,
    const float* __restrict__ tWin, const float* __restrict__ tbin,
    const float* __restrict__ tWhid, const float* __restrict__ tbhid,
    const float* __restrict__ tWout, const float* __restrict__ tbout,
    const uint16_t* __restrict__ wbf, float* __restrict__ out) {
  __shared__ __align__(16) uint16_t h[64 * 512];    // 64 KiB, swizzled rows
  const int tid = threadIdx.x;
  const int wave = tid >> 6, lane = tid & 63;
  const int l15 = lane & 15, lq = lane >> 4;
  const long rowbase = (long)blockIdx.x * 64;

  // ---------------- s MLP ----------------
  dense_in<BF>(wbf + OFF_S_WIN, sWin, sbin, z, rowbase, h, wave, lane);
  dense_relu512<BF>(wbf + OFF_S_WHID, sWhid, sbhid, h, wave, lane);
  dense_relu512<BF>(wbf + OFF_S_WHID + 262144, sWhid + 262144, sbhid + 512, h, wave, lane);

  if (wave < 4) {
    f32x4 acc[4];
    final_layer<BF>(wbf + OFF_S_WOUT, sWout, h, wave, lane, acc);
    const long row = rowbase + wave * 16 + l15;
    float sum = 0.f;
    #pragma unroll
    for (int rt = 0; rt < 4; ++rt) {
      f32x4 bv = *(const f32x4*)(sbout + rt * 16 + lq * 4);
      f32x4 v = acc[rt] + bv;
      v.x = fminf(fmaxf(v.x, -2.f), 2.f);
      v.y = fminf(fmaxf(v.y, -2.f), 2.f);
      v.z = fminf(fmaxf(v.z, -2.f), 2.f);
      v.w = fminf(fmaxf(v.w, -2.f), 2.f);
      sum += v.x + v.y + v.z + v.w;
      *(f32x4*)(out + row * 128 + 64 + rt * 16 + lq * 4) = v;   // stash log_s
    }
    sum += __shfl_xor(sum, 16, 64);
    sum += __shfl_xor(sum, 32, 64);
    if (lane < 16) out[(long)NROWS * 128 + row] = sum;          // log_det
  } else {
    // waves 4..7: copy z1 passthrough (exact fp32)
    #pragma unroll
    for (int i = 0; i < 4; ++i) {
      int v = (wave - 4) * 64 + lane + i * 256;
      int row = v >> 4, kc = (v & 15) * 4;
      *(f32x4*)(out + (rowbase + row) * 128 + kc) =
          *(const f32x4*)(z + (rowbase + row) * 128 + kc);
    }
  }
  __syncthreads();

  // ---------------- t MLP ----------------
  dense_in<BF>(wbf + OFF_T_WIN, tWin, tbin, z, rowbase, h, wave, lane);
  dense_relu512<BF>(wbf + OFF_T_WHID, tWhid, tbhid, h, wave, lane);
  dense_relu512<BF>(wbf + OFF_T_WHID + 262144, tWhid + 262144, tbhid + 512, h, wave, lane);

  if (wave < 4) {
    f32x4 acc[4];
    final_layer<BF>(wbf + OFF_T_WOUT, tWout, h, wave, lane, acc);
    const long row = rowbase + wave * 16 + l15;
    #pragma unroll
    for (int rt = 0; rt < 4; ++rt) {
      f32x4 bv = *(const f32x4*)(tbout + rt * 16 + lq * 4);
      f32x4 tv = acc[rt] + bv;
      const long o = row * 128 + 64 + rt * 16 + lq * 4;
      f32x4 ls = *(const f32x4*)(out + o);   // log_s stashed by s-phase (same thread)
      f32x4 z2 = *(const f32x4*)(z + o);     // z2 = z[:,64:] (same offsets)
      f32x4 r;
      r.x = z2.x * __expf(ls.x) + tv.x;
      r.y = z2.y * __expf(ls.y) + tv.y;
      r.z = z2.z * __expf(ls.z) + tv.z;
      r.w = z2.w * __expf(ls.w) + tv.w;
      *(f32x4*)(out + o) = r;
    }
  }
}

extern "C" void kernel_launch(void* const* d_in, const int* in_sizes, int n_in,
                              void* d_out, int out_size, void* d_ws, size_t ws_size,
                              hipStream_t stream) {
  const float* z     = (const float*)d_in[0];
  const float* sWin  = (const float*)d_in[1];
  const float* sbin  = (const float*)d_in[2];
  const float* sWhid = (const float*)d_in[3];
  const float* sbhid = (const float*)d_in[4];
  const float* sWout = (const float*)d_in[5];
  const float* sbout = (const float*)d_in[6];
  const float* tWin  = (const float*)d_in[7];
  const float* tbin  = (const float*)d_in[8];
  const float* tWhid = (const float*)d_in[9];
  const float* tbhid = (const float*)d_in[10];
  const float* tWout = (const float*)d_in[11];
  const float* tbout = (const float*)d_in[12];
  float* out = (float*)d_out;

  if (ws_size >= (size_t)W_ELEMS * sizeof(uint16_t)) {
    uint16_t* wbf = (uint16_t*)d_ws;
    cvt_weights<<<W_ELEMS / 4 / 256, 256, 0, stream>>>(sWin, sWhid, sWout, tWin, tWhid, tWout, wbf);
    coupling<true><<<NROWS / 64, 512, 0, stream>>>(z, sWin, sbin, sWhid, sbhid, sWout, sbout,
                                                   tWin, tbin, tWhid, tbhid, tWout, tbout, wbf, out);
  } else {
    coupling<false><<<NROWS / 64, 512, 0, stream>>>(z, sWin, sbin, sWhid, sbhid, sWout, sbout,
                                                    tWin, tbin, tWhid, tbhid, tWout, tbout,
                                                    (const uint16_t*)d_in[1], out);
  }
}

// Round 3
// 234.849 us; speedup vs baseline: 1.5760x; 1.5760x over previous
//
#include <hip/hip_runtime.h>
#include <stdint.h>

// AffineCoupling: B=65536 rows, DIM=128, D_IN=64, HID=512, 2 extra hidden layers.
// Fused bf16-MFMA. 128 rows/block (512 blocks), 8 waves; hidden layers: each
// wave owns 64 neurons x 128 rows (4x8 16x16x32 frags) -> per k-step 4 A-frag
// global loads + 8 B-frag LDS reads feed 32 MFMAs, keeping per-CU TCP (~26B/cyc)
// and DS (~53B/cyc) under their ceilings (64 / 85 B/cyc). h = 128KiB dynamic LDS.
// log_s stashed in out's z2 region between s- and t-MLP (same-thread RAW).

#define NROWS 65536
#define RPB   128
#define NBLK  (NROWS / RPB)

// bf16 weight scratch layout (element offsets in d_ws)
#define OFF_S_WIN   0
#define OFF_S_WHID  32768
#define OFF_S_WOUT  557056
#define OFF_T_WIN   589824
#define OFF_T_WHID  622592
#define OFF_T_WOUT  1146880
#define W_ELEMS     1179648

typedef __attribute__((ext_vector_type(8))) short short8;
typedef __attribute__((ext_vector_type(4))) float f32x4;

__device__ __forceinline__ uint32_t f2bf1(float f) {
  uint32_t u = __float_as_uint(f);
  return (u + 0x7fffu + ((u >> 16) & 1u)) >> 16;   // RNE
}
__device__ __forceinline__ uint32_t pk2bf(float a, float b) {
  return f2bf1(a) | (f2bf1(b) << 16);
}

// ---------------- weight fp32 -> bf16 prologue ----------------
__global__ void cvt_weights(const float* __restrict__ sWin, const float* __restrict__ sWhid,
                            const float* __restrict__ sWout, const float* __restrict__ tWin,
                            const float* __restrict__ tWhid, const float* __restrict__ tWout,
                            uint16_t* __restrict__ wbf) {
  int g = blockIdx.x * blockDim.x + threadIdx.x;
  int e = g * 4;
  if (e >= W_ELEMS) return;
  const float* src; int off;
  if      (e < OFF_S_WHID) { src = sWin;  off = e; }
  else if (e < OFF_S_WOUT) { src = sWhid; off = e - OFF_S_WHID; }
  else if (e < OFF_T_WIN)  { src = sWout; off = e - OFF_S_WOUT; }
  else if (e < OFF_T_WHID) { src = tWin;  off = e - OFF_T_WIN; }
  else if (e < OFF_T_WOUT) { src = tWhid; off = e - OFF_T_WHID; }
  else                     { src = tWout; off = e - OFF_T_WOUT; }
  f32x4 v = *(const f32x4*)(src + off);
  uint2 r; r.x = pk2bf(v.x, v.y); r.y = pk2bf(v.z, v.w);
  *(uint2*)(wbf + e) = r;
}

// ---------------- fragment loaders ----------------
// A-frag (weights, row-major [M][K]): lane l supplies W[m=base+(l&15)][k=(l>>4)*8+j]
template<bool BF>
__device__ __forceinline__ short8 ldW(const uint16_t* __restrict__ wb,
                                      const float* __restrict__ wf, int idx) {
  if (BF) {
    return *(const short8*)(wb + idx);
  } else {  // fallback: convert fp32 weights on the fly
    f32x4 x = *(const f32x4*)(wf + idx);
    f32x4 y = *(const f32x4*)(wf + idx + 4);
    short8 r;
    r[0] = (short)f2bf1(x.x); r[1] = (short)f2bf1(x.y);
    r[2] = (short)f2bf1(x.z); r[3] = (short)f2bf1(x.w);
    r[4] = (short)f2bf1(y.x); r[5] = (short)f2bf1(y.y);
    r[6] = (short)f2bf1(y.z); r[7] = (short)f2bf1(y.w);
    return r;
  }
}

// B-frag (activations h^T from LDS, row stride 1024B):
// XOR swizzle (row&7)<<4 breaks same-bank column access (2-way = free).
__device__ __forceinline__ short8 ldsB(const uint16_t* buf, int row, int k) {
  int byte = (row * 1024 + k * 2) ^ ((row & 7) << 4);
  return *(const short8*)((const char*)buf + byte);
}

// ---------------- epilogue: bias + relu + pack + swizzled LDS store ----------------
__device__ __forceinline__ void store_h(f32x4 acc[4][8], const float* __restrict__ bias,
                                        uint16_t* hdst, int wave, int lane) {
  const int l15 = lane & 15, lq = lane >> 4;
  __syncthreads();   // all waves done READING h (h is read+written in place)
  #pragma unroll
  for (int rt = 0; rt < 4; ++rt) {
    const int n0 = wave * 64 + rt * 16 + lq * 4;
    f32x4 bv = *(const f32x4*)(bias + n0);
    #pragma unroll
    for (int ct = 0; ct < 8; ++ct) {
      const int row = ct * 16 + l15;
      f32x4 v = acc[rt][ct] + bv;
      uint2 p;
      p.x = pk2bf(fmaxf(v.x, 0.f), fmaxf(v.y, 0.f));
      p.y = pk2bf(fmaxf(v.z, 0.f), fmaxf(v.w, 0.f));
      int byte = (row * 1024 + n0 * 2) ^ ((row & 7) << 4);
      *(uint2*)((char*)hdst + byte) = p;
    }
  }
  __syncthreads();
}

// ---------------- layer 1: h = relu(W @ z1^T + b), K=64, B built from global z ----------------
template<bool BF>
__device__ __forceinline__ void dense_in(
    const uint16_t* __restrict__ wb, const float* __restrict__ wf,
    const float* __restrict__ bias, const float* __restrict__ z, long rowbase,
    uint16_t* hdst, int wave, int lane) {
  const int l15 = lane & 15, lq = lane >> 4;
  f32x4 acc[4][8];
  #pragma unroll
  for (int rt = 0; rt < 4; ++rt)
    #pragma unroll
    for (int ct = 0; ct < 8; ++ct) acc[rt][ct] = (f32x4){0.f, 0.f, 0.f, 0.f};
  const int wbase = (wave * 64 + l15) * 64 + lq * 8;
  #pragma unroll
  for (int k0 = 0; k0 < 64; k0 += 32) {
    short8 a[4];
    #pragma unroll
    for (int rt = 0; rt < 4; ++rt) a[rt] = ldW<BF>(wb, wf, wbase + rt * 1024 + k0);
    #pragma unroll
    for (int ct = 0; ct < 8; ++ct) {
      const float* zp = z + (rowbase + ct * 16 + l15) * 128 + lq * 8 + k0;
      f32x4 u = *(const f32x4*)zp;
      f32x4 v = *(const f32x4*)(zp + 4);
      short8 b;
      b[0] = (short)f2bf1(u.x); b[1] = (short)f2bf1(u.y);
      b[2] = (short)f2bf1(u.z); b[3] = (short)f2bf1(u.w);
      b[4] = (short)f2bf1(v.x); b[5] = (short)f2bf1(v.y);
      b[6] = (short)f2bf1(v.z); b[7] = (short)f2bf1(v.w);
      #pragma unroll
      for (int rt = 0; rt < 4; ++rt)
        acc[rt][ct] = __builtin_amdgcn_mfma_f32_16x16x32_bf16(a[rt], b, acc[rt][ct], 0, 0, 0);
    }
  }
  store_h(acc, bias, hdst, wave, lane);
}

// ---------------- hidden layer: h = relu(W @ h^T + b), K=512, A-frag prefetch ----------------
template<bool BF>
__device__ __forceinline__ void dense_relu512(
    const uint16_t* __restrict__ wb, const float* __restrict__ wf,
    const float* __restrict__ bias, uint16_t* hbuf, int wave, int lane) {
  const int l15 = lane & 15, lq = lane >> 4;
  f32x4 acc[4][8];
  #pragma unroll
  for (int rt = 0; rt < 4; ++rt)
    #pragma unroll
    for (int ct = 0; ct < 8; ++ct) acc[rt][ct] = (f32x4){0.f, 0.f, 0.f, 0.f};
  const int wbase = (wave * 64 + l15) * 512 + lq * 8;

  short8 an[4];
  #pragma unroll
  for (int rt = 0; rt < 4; ++rt) an[rt] = ldW<BF>(wb, wf, wbase + rt * 8192);

  #pragma unroll 2
  for (int k0 = 0; k0 < 512; k0 += 32) {
    short8 ac[4];
    #pragma unroll
    for (int rt = 0; rt < 4; ++rt) ac[rt] = an[rt];
    if (k0 + 32 < 512) {
      #pragma unroll
      for (int rt = 0; rt < 4; ++rt)
        an[rt] = ldW<BF>(wb, wf, wbase + rt * 8192 + k0 + 32);
    }
    #pragma unroll
    for (int ct = 0; ct < 8; ++ct) {
      short8 b = ldsB(hbuf, ct * 16 + l15, lq * 8 + k0);
      #pragma unroll
      for (int rt = 0; rt < 4; ++rt)
        acc[rt][ct] = __builtin_amdgcn_mfma_f32_16x16x32_bf16(ac[rt], b, acc[rt][ct], 0, 0, 0);
    }
  }
  store_h(acc, bias, hbuf, wave, lane);
}

// ---------------- output layer: 64 neurons x 32 rows per wave, waves 0..3 ----------------
template<bool BF>
__device__ __forceinline__ void final_layer(
    const uint16_t* __restrict__ wb, const float* __restrict__ wf,
    const uint16_t* hbuf, int wave, int lane, f32x4 acc[4][2]) {
  const int l15 = lane & 15, lq = lane >> 4;
  #pragma unroll
  for (int rt = 0; rt < 4; ++rt)
    #pragma unroll
    for (int ct = 0; ct < 2; ++ct) acc[rt][ct] = (f32x4){0.f, 0.f, 0.f, 0.f};
  const int wbase = l15 * 512 + lq * 8;
  #pragma unroll 4
  for (int k0 = 0; k0 < 512; k0 += 32) {
    short8 a[4];
    #pragma unroll
    for (int rt = 0; rt < 4; ++rt) a[rt] = ldW<BF>(wb, wf, wbase + rt * 8192 + k0);
    #pragma unroll
    for (int ct = 0; ct < 2; ++ct) {
      short8 b = ldsB(hbuf, wave * 32 + ct * 16 + l15, lq * 8 + k0);
      #pragma unroll
      for (int rt = 0; rt < 4; ++rt)
        acc[rt][ct] = __builtin_amdgcn_mfma_f32_16x16x32_bf16(a[rt], b, acc[rt][ct], 0, 0, 0);
    }
  }
}

// ---------------- fused coupling kernel: 128 rows/block, 8 waves ----------------
template<bool BF>
__global__ __launch_bounds__(512, 2) void coupling(
    const float* __restrict__ z,
    const float* __restrict__ sWin, const float* __restrict__ sbin,
    const float* __restrict__ sWhid, const float* __restrict__ sbhid,
    const float* __restrict__ sWout, const float* __restrict__ sbout,
    const float* __restrict__ tWin, const float* __restrict__ tbin,
    const float* __restrict__ tWhid, const float* __restrict__ tbhid,
    const float* __restrict__ tWout, const float* __restrict__ tbout,
    const uint16_t* __restrict__ wbf, float* __restrict__ out) {
  extern __shared__ __align__(16) uint16_t h[];     // RPB x 512 bf16 = 128 KiB, swizzled
  const int tid = threadIdx.x;
  const int wave = tid >> 6, lane = tid & 63;
  const int l15 = lane & 15, lq = lane >> 4;
  const long rowbase = (long)blockIdx.x * RPB;

  // ---------------- s MLP ----------------
  dense_in<BF>(wbf + OFF_S_WIN, sWin, sbin, z, rowbase, h, wave, lane);
  dense_relu512<BF>(wbf + OFF_S_WHID, sWhid, sbhid, h, wave, lane);
  dense_relu512<BF>(wbf + OFF_S_WHID + 262144, sWhid + 262144, sbhid + 512, h, wave, lane);

  if (wave < 4) {
    f32x4 acc[4][2];
    final_layer<BF>(wbf + OFF_S_WOUT, sWout, h, wave, lane, acc);
    #pragma unroll
    for (int ct = 0; ct < 2; ++ct) {
      const long row = rowbase + wave * 32 + ct * 16 + l15;
      float sum = 0.f;
      #pragma unroll
      for (int rt = 0; rt < 4; ++rt) {
        f32x4 bv = *(const f32x4*)(sbout + rt * 16 + lq * 4);
        f32x4 v = acc[rt][ct] + bv;
        v.x = fminf(fmaxf(v.x, -2.f), 2.f);
        v.y = fminf(fmaxf(v.y, -2.f), 2.f);
        v.z = fminf(fmaxf(v.z, -2.f), 2.f);
        v.w = fminf(fmaxf(v.w, -2.f), 2.f);
        sum += v.x + v.y + v.z + v.w;
        *(f32x4*)(out + row * 128 + 64 + rt * 16 + lq * 4) = v;   // stash log_s
      }
      sum += __shfl_xor(sum, 16, 64);
      sum += __shfl_xor(sum, 32, 64);
      if (lane < 16) out[(long)NROWS * 128 + row] = sum;          // log_det
    }
  } else {
    // waves 4..7: copy z1 passthrough (exact fp32), 128 rows x 64 cols
    #pragma unroll
    for (int i = 0; i < 8; ++i) {
      int v = (wave - 4) * 64 + lane + i * 256;
      int row = v >> 4, kc = (v & 15) * 4;
      *(f32x4*)(out + (rowbase + row) * 128 + kc) =
          *(const f32x4*)(z + (rowbase + row) * 128 + kc);
    }
  }
  __syncthreads();

  // ---------------- t MLP ----------------
  dense_in<BF>(wbf + OFF_T_WIN, tWin, tbin, z, rowbase, h, wave, lane);
  dense_relu512<BF>(wbf + OFF_T_WHID, tWhid, tbhid, h, wave, lane);
  dense_relu512<BF>(wbf + OFF_T_WHID + 262144, tWhid + 262144, tbhid + 512, h, wave, lane);

  if (wave < 4) {
    f32x4 acc[4][2];
    final_layer<BF>(wbf + OFF_T_WOUT, tWout, h, wave, lane, acc);
    #pragma unroll
    for (int ct = 0; ct < 2; ++ct) {
      const long row = rowbase + wave * 32 + ct * 16 + l15;
      #pragma unroll
      for (int rt = 0; rt < 4; ++rt) {
        f32x4 bv = *(const f32x4*)(tbout + rt * 16 + lq * 4);
        f32x4 tv = acc[rt][ct] + bv;
        const long o = row * 128 + 64 + rt * 16 + lq * 4;
        f32x4 ls = *(const f32x4*)(out + o);   // log_s stashed by s-phase (same thread)
        f32x4 z2 = *(const f32x4*)(z + o);     // z2 = z[:,64:] (same offsets)
        f32x4 r;
        r.x = z2.x * __expf(ls.x) + tv.x;
        r.y = z2.y * __expf(ls.y) + tv.y;
        r.z = z2.z * __expf(ls.z) + tv.z;
        r.w = z2.w * __expf(ls.w) + tv.w;
        *(f32x4*)(out + o) = r;
      }
    }
  }
}

extern "C" void kernel_launch(void* const* d_in, const int* in_sizes, int n_in,
                              void* d_out, int out_size, void* d_ws, size_t ws_size,
                              hipStream_t stream) {
  const float* z     = (const float*)d_in[0];
  const float* sWin  = (const float*)d_in[1];
  const float* sbin  = (const float*)d_in[2];
  const float* sWhid = (const float*)d_in[3];
  const float* sbhid = (const float*)d_in[4];
  const float* sWout = (const float*)d_in[5];
  const float* sbout = (const float*)d_in[6];
  const float* tWin  = (const float*)d_in[7];
  const float* tbin  = (const float*)d_in[8];
  const float* tWhid = (const float*)d_in[9];
  const float* tbhid = (const float*)d_in[10];
  const float* tWout = (const float*)d_in[11];
  const float* tbout = (const float*)d_in[12];
  float* out = (float*)d_out;
  const size_t lds_bytes = (size_t)RPB * 512 * sizeof(uint16_t);   // 128 KiB

  if (ws_size >= (size_t)W_ELEMS * sizeof(uint16_t)) {
    uint16_t* wbf = (uint16_t*)d_ws;
    cvt_weights<<<W_ELEMS / 4 / 256, 256, 0, stream>>>(sWin, sWhid, sWout, tWin, tWhid, tWout, wbf);
    coupling<true><<<NBLK, 512, lds_bytes, stream>>>(z, sWin, sbin, sWhid, sbhid, sWout, sbout,
                                                     tWin, tbin, tWhid, tbhid, tWout, tbout, wbf, out);
  } else {
    coupling<false><<<NBLK, 512, lds_bytes, stream>>>(z, sWin, sbin, sWhid, sbhid, sWout, sbout,
                                                      tWin, tbin, tWhid, tbhid, tWout, tbout,
                                                      (const uint16_t*)d_in[1], out);
  }
}